// Round 1
// baseline (505.814 us; speedup 1.0000x reference)
//
#include <hip/hip_runtime.h>
#include <hip/hip_cooperative_groups.h>
#include <math.h>

namespace cg = cooperative_groups;

// Problem constants (from reference): feature_map [16,64,224,224], points [16,1024,2]
#define BB   16
#define HH   224
#define WW   224
#define NPTS 1024
#define KS   23      // int(224*0.1)=22 -> +1 = 23
#define HALF 11
#define SIGMA2_2 18.0f  // 2*sigma^2, sigma=3
#define PIX  (BB * HH * WW)   // 802,816

#define GRID_BLOCKS 1024     // 4 blocks/CU on 256 CUs -> guaranteed co-resident
#define BLOCK 256
#define NTHREADS (GRID_BLOCKS * BLOCK)  // 262,144

// L1-normalized 1D gaussian weights. ALL indices compile-time constant after
// full unroll -> w[] stays in VGPRs (lane-varying index would force scratch).
__device__ __forceinline__ void gauss_weights(float* w) {
    float s = 0.0f;
#pragma unroll
    for (int t = 0; t < KS; ++t) {
        float ax = (float)(t - HALF);
        float v = __expf(-(ax * ax) / SIGMA2_2);
        w[t] = v;
        s += v;
    }
    float inv = 1.0f / s;
#pragma unroll
    for (int t = 0; t < KS; ++t) w[t] *= inv;
}

// One cooperative kernel: zero -> scatter -> hconv -> vconv, separated by
// grid.sync(). Removes 4 dispatch boundaries + the memset node vs the
// 4-launch version; total real work is ~16 MB of L2-resident traffic.
__global__ __launch_bounds__(BLOCK, 4) void fused(const float* __restrict__ pts,
                                                  float* __restrict__ out,
                                                  float* __restrict__ cnt,
                                                  float* __restrict__ tmp) {
    cg::grid_group grid = cg::this_grid();
    const int tid = blockIdx.x * BLOCK + threadIdx.x;

    // ---- phase 0: zero the count grid (ws is poisoned 0xAA each call) ----
    {
        float4 z = make_float4(0.f, 0.f, 0.f, 0.f);
        float4* c4 = (float4*)cnt;
        for (int i = tid; i < PIX / 4; i += NTHREADS) c4[i] = z;
    }
    grid.sync();

    // ---- phase 1: scatter point counts ----
    if (tid < BB * NPTS) {
        int b = tid >> 10;  // NPTS = 1024
        float px = pts[2 * tid + 0];
        float py = pts[2 * tid + 1];
        int x = (int)(px * (float)WW);  // trunc of nonneg == astype(int32)
        int y = (int)(py * (float)HH);
        if ((unsigned)x < (unsigned)WW && (unsigned)y < (unsigned)HH)
            atomicAdd(&cnt[(b * HH + y) * WW + x], 1.0f);
    }
    grid.sync();

    float w[KS];
    gauss_weights(w);

    // ---- phase 2: horizontal 23-tap conv, zero padding ----
    for (int idx = tid; idx < PIX; idx += NTHREADS) {
        int j = idx % WW;
        int rowbase = idx - j;
        float acc = 0.0f;
#pragma unroll
        for (int t = 0; t < KS; ++t) {
            int x = j + t - HALF;
            float v = ((unsigned)x < (unsigned)WW) ? cnt[rowbase + x] : 0.0f;
            acc = fmaf(v, w[t], acc);
        }
        tmp[idx] = acc;
    }
    grid.sync();

    // ---- phase 3: vertical 23-tap conv, zero padding ----
    for (int idx = tid; idx < PIX; idx += NTHREADS) {
        int j = idx % WW;
        int rem = idx / WW;
        int i = rem % HH;
        int b = rem / HH;
        const float* base = tmp + (size_t)b * HH * WW + j;
        float acc = 0.0f;
#pragma unroll
        for (int t = 0; t < KS; ++t) {
            int y = i + t - HALF;
            float v = ((unsigned)y < (unsigned)HH) ? base[(size_t)y * WW] : 0.0f;
            acc = fmaf(v, w[t], acc);
        }
        out[idx] = acc;
    }
}

// ---- fallback path (old 4-dispatch version) in case cooperative launch
// ---- is rejected at capture time ----
__global__ void scatter_counts(const float* __restrict__ pts, float* __restrict__ cnt) {
    int idx = blockIdx.x * blockDim.x + threadIdx.x;
    if (idx >= BB * NPTS) return;
    int b = idx / NPTS;
    float px = pts[2 * idx + 0];
    float py = pts[2 * idx + 1];
    int x = (int)(px * (float)WW);
    int y = (int)(py * (float)HH);
    if ((unsigned)x >= WW || (unsigned)y >= HH) return;
    atomicAdd(&cnt[(b * HH + y) * WW + x], 1.0f);
}

__global__ void hconv(const float* __restrict__ cnt, float* __restrict__ tmp) {
    int idx = blockIdx.x * blockDim.x + threadIdx.x;
    if (idx >= BB * HH * WW) return;
    float w[KS];
    gauss_weights(w);
    int j = idx % WW;
    int rowbase = idx - j;
    float acc = 0.0f;
#pragma unroll
    for (int t = 0; t < KS; ++t) {
        int x = j + t - HALF;
        float v = ((unsigned)x < (unsigned)WW) ? cnt[rowbase + x] : 0.0f;
        acc = fmaf(v, w[t], acc);
    }
    tmp[idx] = acc;
}

__global__ void vconv(const float* __restrict__ tmp, float* __restrict__ out) {
    int idx = blockIdx.x * blockDim.x + threadIdx.x;
    if (idx >= BB * HH * WW) return;
    float w[KS];
    gauss_weights(w);
    int j = idx % WW;
    int rem = idx / WW;
    int i = rem % HH;
    int b = rem / HH;
    const float* base = tmp + (size_t)b * HH * WW + j;
    float acc = 0.0f;
#pragma unroll
    for (int t = 0; t < KS; ++t) {
        int y = i + t - HALF;
        float v = ((unsigned)y < (unsigned)HH) ? base[(size_t)y * WW] : 0.0f;
        acc = fmaf(v, w[t], acc);
    }
    out[idx] = acc;
}

extern "C" void kernel_launch(void* const* d_in, const int* in_sizes, int n_in,
                              void* d_out, int out_size, void* d_ws, size_t ws_size,
                              hipStream_t stream) {
    // d_in[0] = feature_map (values unused, only shape matters)
    const float* pts = (const float*)d_in[1];
    float* out = (float*)d_out;

    float* cnt = (float*)d_ws;     // [B,H,W]
    float* tmp = cnt + PIX;        // [B,H,W]  (2*PIX*4 = 6.4 MB of ws)

    void* args[] = {(void*)&pts, (void*)&out, (void*)&cnt, (void*)&tmp};
    hipError_t err = hipLaunchCooperativeKernel((const void*)fused,
                                                dim3(GRID_BLOCKS), dim3(BLOCK),
                                                args, 0, stream);
    if (err != hipSuccess) {
        // fallback: classic 4-dispatch pipeline
        hipMemsetAsync(cnt, 0, (size_t)PIX * sizeof(float), stream);
        scatter_counts<<<(BB * NPTS + 255) / 256, 256, 0, stream>>>(pts, cnt);
        hconv<<<(PIX + 255) / 256, 256, 0, stream>>>(cnt, tmp);
        vconv<<<(PIX + 255) / 256, 256, 0, stream>>>(tmp, out);
    }
}

// Round 2
// 233.588 us; speedup vs baseline: 2.1654x; 2.1654x over previous
//
#include <hip/hip_runtime.h>
#include <math.h>

// Problem constants (from reference): feature_map [16,64,224,224], points [16,1024,2]
#define BB   16
#define HH   224
#define WW   224
#define NPTS 1024
#define KS   23      // int(224*0.1)=22 -> +1 = 23
#define HALF 11
#define SIGMA2_2 18.0f  // 2*sigma^2, sigma=3

// Tile geometry: each block produces a 32x32 output tile.
// 224/32 = 7 -> 7x7 = 49 tiles/batch, 784 blocks total (~3 blocks/CU).
#define TH 32
#define TW 32
#define IN_H (TH + 2 * HALF)   // 54
#define IN_W (TW + 2 * HALF)   // 54
#define TILES_X (WW / TW)      // 7
#define TILES_PER_B (TILES_X * (HH / TH))  // 49

// L1-normalized 1D gaussian weights. ALL indices compile-time constant after
// full unroll -> w[] stays in VGPRs.
__device__ __forceinline__ void gauss_weights(float* w) {
    float s = 0.0f;
#pragma unroll
    for (int t = 0; t < KS; ++t) {
        float ax = (float)(t - HALF);
        float v = __expf(-(ax * ax) / SIGMA2_2);
        w[t] = v;
        s += v;
    }
    float inv = 1.0f / s;
#pragma unroll
    for (int t = 0; t < KS; ++t) w[t] *= inv;
}

// Single-dispatch fused saliency:
//  phase 0: zero LDS count tile (54x54, covers output tile + 11-halo)
//  phase 1: scan this batch's 1024 points; LDS-atomicAdd the ~60 that land
//           in the halo region (equivalent to the global scatter, restricted
//           to this tile's support)
//  phase 2: horizontal 23-tap conv, LDS cnt -> LDS hbuf (54x32)
//  phase 3: vertical 23-tap conv, LDS hbuf -> global out (32x32)
// Zero-padding is implicit: halo cells outside the image get no points and
// stay zero, exactly matching the reference's padded-scatter-then-crop.
__global__ __launch_bounds__(256) void saliency_fused(const float* __restrict__ pts,
                                                      float* __restrict__ out) {
    __shared__ float cnt[IN_H * IN_W];   // 2916 f = 11.7 KB
    __shared__ float hbuf[IN_H * TW];    // 1728 f = 6.9 KB

    const int blk = blockIdx.x;          // 0..783
    const int b   = blk / TILES_PER_B;
    const int t49 = blk % TILES_PER_B;
    const int r0  = (t49 / TILES_X) * TH;   // output tile origin (row)
    const int c0  = (t49 % TILES_X) * TW;   // output tile origin (col)
    const int gr0 = r0 - HALF;              // input (halo) region origin
    const int gc0 = c0 - HALF;
    const int tid = threadIdx.x;

    // ---- phase 0: zero the LDS count tile ----
    for (int i = tid; i < IN_H * IN_W; i += 256) cnt[i] = 0.0f;
    __syncthreads();

    // ---- phase 1: local scatter of this batch's points ----
    {
        const float* pb = pts + (size_t)b * NPTS * 2;
        for (int p = tid; p < NPTS; p += 256) {
            float px = pb[2 * p + 0];
            float py = pb[2 * p + 1];
            int x = (int)(px * (float)WW);  // trunc of nonneg == astype(int32)
            int y = (int)(py * (float)HH);
            if ((unsigned)x < (unsigned)WW && (unsigned)y < (unsigned)HH) {
                int lx = x - gc0;
                int ly = y - gr0;
                if ((unsigned)lx < (unsigned)IN_W && (unsigned)ly < (unsigned)IN_H)
                    atomicAdd(&cnt[ly * IN_W + lx], 1.0f);
            }
        }
    }
    __syncthreads();

    float w[KS];
    gauss_weights(w);

    // ---- phase 2: horizontal conv over the 54 halo rows, 32 output cols ----
    // hbuf[r][c] = sum_t cnt[r][c+t] * w[t]   (local col c == global col c0+c)
    for (int i = tid; i < IN_H * TW; i += 256) {
        int r = i / TW;
        int c = i % TW;
        const float* row = &cnt[r * IN_W + c];
        float acc = 0.0f;
#pragma unroll
        for (int t = 0; t < KS; ++t) acc = fmaf(row[t], w[t], acc);
        hbuf[r * TW + c] = acc;
    }
    __syncthreads();

    // ---- phase 3: vertical conv, write 32x32 output tile ----
    // out[r0+r][c0+c] = sum_t hbuf[r+t][c] * w[t]
    for (int i = tid; i < TH * TW; i += 256) {
        int r = i / TW;
        int c = i % TW;
        const float* col = &hbuf[r * TW + c];
        float acc = 0.0f;
#pragma unroll
        for (int t = 0; t < KS; ++t) acc = fmaf(col[t * TW], w[t], acc);
        out[((size_t)b * HH + (r0 + r)) * WW + (c0 + c)] = acc;
    }
}

extern "C" void kernel_launch(void* const* d_in, const int* in_sizes, int n_in,
                              void* d_out, int out_size, void* d_ws, size_t ws_size,
                              hipStream_t stream) {
    // d_in[0] = feature_map (values unused, only shape matters)
    const float* pts = (const float*)d_in[1];
    float* out = (float*)d_out;

    saliency_fused<<<BB * TILES_PER_B, 256, 0, stream>>>(pts, out);
}